// Round 4
// baseline (290.825 us; speedup 1.0000x reference)
//
#include <hip/hip_runtime.h>

typedef __bf16 bf16_t;
typedef __bf16 bf16x8 __attribute__((ext_vector_type(8)));
typedef __bf16 bf16x4 __attribute__((ext_vector_type(4)));
typedef float  f32x4  __attribute__((ext_vector_type(4)));

#define B_DIM 4
#define S_DIM 4096
#define D_DIM 1024
#define M_DIM (B_DIM * S_DIM)   // 16384 rows

#define CHUNK 64   // scan output steps per block
#define WARM  24   // scan warm-up steps

// ---------------- LayerNorm fp32 -> bf16, one wave per row ----------------
__global__ __launch_bounds__(64) void ln_kernel(
    const float* __restrict__ x, const float* __restrict__ gamma,
    const float* __restrict__ beta, bf16_t* __restrict__ h) {
  const int row  = blockIdx.x;
  const int lane = threadIdx.x;
  const float4* xr = (const float4*)(x + (size_t)row * D_DIM);
  float4 v[4];
  float s = 0.f, s2 = 0.f;
#pragma unroll
  for (int j = 0; j < 4; ++j) {
    v[j] = xr[j * 64 + lane];
    s += v[j].x + v[j].y + v[j].z + v[j].w;
    s2 = fmaf(v[j].x, v[j].x, s2);
    s2 = fmaf(v[j].y, v[j].y, s2);
    s2 = fmaf(v[j].z, v[j].z, s2);
    s2 = fmaf(v[j].w, v[j].w, s2);
  }
#pragma unroll
  for (int off = 32; off; off >>= 1) {
    s  += __shfl_xor(s, off);
    s2 += __shfl_xor(s2, off);
  }
  const float mu  = s * (1.f / (float)D_DIM);
  const float var = fmaf(-mu, mu, s2 * (1.f / (float)D_DIM));
  const float inv = rsqrtf(var + 1e-5f);
  bf16_t* hr = h + (size_t)row * D_DIM;
#pragma unroll
  for (int j = 0; j < 4; ++j) {
    const float4 g4 = ((const float4*)gamma)[j * 64 + lane];
    const float4 b4 = ((const float4*)beta)[j * 64 + lane];
    bf16x4 o;
    o[0] = (bf16_t)fmaf((v[j].x - mu) * inv, g4.x, b4.x);
    o[1] = (bf16_t)fmaf((v[j].y - mu) * inv, g4.y, b4.y);
    o[2] = (bf16_t)fmaf((v[j].z - mu) * inv, g4.z, b4.z);
    o[3] = (bf16_t)fmaf((v[j].w - mu) * inv, g4.w, b4.w);
    ((bf16x4*)hr)[j * 64 + lane] = o;
  }
}

// ------------- W [K][N] fp32  ->  WT [N][K] bf16 (tiled transpose) --------
__global__ __launch_bounds__(256) void transpose_kernel(
    const float* __restrict__ W, bf16_t* __restrict__ WT) {
  __shared__ float tile[32][33];
  const int tx = threadIdx.x & 31;
  const int ty = threadIdx.x >> 5;
  const int bn = blockIdx.x * 32;
  const int bk = blockIdx.y * 32;
#pragma unroll
  for (int i = 0; i < 32; i += 8)
    tile[ty + i][tx] = W[(size_t)(bk + ty + i) * D_DIM + bn + tx];
  __syncthreads();
#pragma unroll
  for (int i = 0; i < 32; i += 8)
    WT[(size_t)(bn + ty + i) * D_DIM + bk + tx] = (bf16_t)tile[tx][ty + i];
}

// ========== bf16 NT GEMM, 256x256 tile, direct-from-global fragments ======
// C[M][N] = A[M][K] * BT[N][K]^T ; MODE 0: bf16(acc+bias); MODE 1: f32 +x
// No LDS, no barriers: each wave streams its MFMA fragments straight from
// global (L2-resident B panel; A panel reused 4x by co-XCD blocks).
template <int MODE>
__global__ __launch_bounds__(512, 2) void gemm_nt_kernel(
    const bf16_t* __restrict__ A, const bf16_t* __restrict__ BT,
    const float* __restrict__ bias, const float* __restrict__ xres,
    void* __restrict__ Cout) {
  const int tid  = threadIdx.x;
  const int lane = tid & 63;
  const int wave = tid >> 6;           // 0..7
  const int wr = wave >> 2;            // 0..1 (M half: 128 rows)
  const int wc = wave & 3;             // 0..3 (N quarter: 64 cols)
  const int bid = blockIdx.x;
  const int swz = (bid & 7) * 32 + (bid >> 3);   // 256 blocks, 8 XCDs
  const int m0 = (swz >> 2) * 256;
  const int n0 = (swz & 3) * 256;

  // fragment sources: lane holds row (lane&15), k-elems (lane>>4)*8..+7
  const int frow = lane & 15;
  const int fk   = (lane >> 4) << 3;
  const bf16_t* aP = A  + (size_t)(m0 + wr * 128 + frow) * D_DIM + fk;
  const bf16_t* bP = BT + (size_t)(n0 + wc * 64 + frow) * D_DIM + fk;

  f32x4 acc[8][4];
#pragma unroll
  for (int m = 0; m < 8; ++m)
#pragma unroll
    for (int n = 0; n < 4; ++n) acc[m][n] = (f32x4){0.f, 0.f, 0.f, 0.f};

  for (int k0 = 0; k0 < D_DIM; k0 += 32) {
    bf16x8 af[8], bfr[4];
#pragma unroll
    for (int m = 0; m < 8; ++m)
      af[m] = *(const bf16x8*)(aP + k0 + (size_t)m * 16 * D_DIM);
#pragma unroll
    for (int n = 0; n < 4; ++n)
      bfr[n] = *(const bf16x8*)(bP + k0 + (size_t)n * 16 * D_DIM);
#pragma unroll
    for (int m = 0; m < 8; ++m)
#pragma unroll
      for (int n = 0; n < 4; ++n)
        acc[m][n] = __builtin_amdgcn_mfma_f32_16x16x32_bf16(
            af[m], bfr[n], acc[m][n], 0, 0, 0);
  }

  // epilogue: C/D layout col = lane&15, row = (lane>>4)*4 + r
  const int rbase = m0 + wr * 128 + ((lane >> 4) << 2);
  const int cbase = n0 + wc * 64 + (lane & 15);
#pragma unroll
  for (int n = 0; n < 4; ++n) {
    const int col = cbase + n * 16;
    const float bn = bias[col];
#pragma unroll
    for (int m = 0; m < 8; ++m) {
      const int row = rbase + m * 16;
#pragma unroll
      for (int r = 0; r < 4; ++r) {
        const size_t idx = (size_t)(row + r) * D_DIM + col;
        if (MODE == 0)
          ((bf16_t*)Cout)[idx] = (bf16_t)(acc[m][n][r] + bn);
        else
          ((float*)Cout)[idx] = xres[idx] + acc[m][n][r] + bn;
      }
    }
  }
}

// ---------------- chunked chaotic scan, one wave per (batch, chunk) -------
__global__ __launch_bounds__(64) void scan_kernel(
    const bf16_t* __restrict__ c, bf16_t* __restrict__ y) {
  const int b     = blockIdx.y;
  const int chunk = blockIdx.x;
  const int t0    = chunk * CHUNK;
  const int start = (chunk == 0) ? 0 : t0 - WARM;
  const int tend  = t0 + CHUNK;
  const int lane  = threadIdx.x;

  float zre[8], zim[8];
#pragma unroll
  for (int j = 0; j < 8; ++j) { zre[j] = 0.f; zim[j] = 0.f; }

  const bf16_t* crow = c + ((size_t)b * S_DIM + start) * D_DIM;
  bf16x8 cr = ((const bf16x8*)crow)[lane];
  bf16x8 ci = ((const bf16x8*)(crow + 512))[lane];

  for (int t = start; t < tend; ++t) {
    bf16x8 crn = cr, cin = ci;
    if (t + 1 < tend) {
      const bf16_t* nrow = c + ((size_t)b * S_DIM + (t + 1)) * D_DIM;
      crn = ((const bf16x8*)nrow)[lane];
      cin = ((const bf16x8*)(nrow + 512))[lane];
    }
    float nr[8], ni[8];
    float ss = 0.f;
#pragma unroll
    for (int j = 0; j < 8; ++j) {
      const float a  = zre[j], bb = zim[j];
      const float rr = fmaf(a, a, fmaf(-bb, bb, (float)cr[j]));
      const float ii = fmaf(2.f * a, bb, (float)ci[j]);
      nr[j] = rr; ni[j] = ii;
      ss = fmaf(rr, rr, ss);
      ss = fmaf(ii, ii, ss);
    }
#pragma unroll
    for (int off = 32; off; off >>= 1) ss += __shfl_xor(ss, off);
    const float nrm = sqrtf(ss + 1e-12f);
    const float sc  = 2.0f / fmaxf(nrm, 2.0f);
#pragma unroll
    for (int j = 0; j < 8; ++j) { zre[j] = nr[j] * sc; zim[j] = ni[j] * sc; }
    if (t >= t0) {
      bf16_t* yrow = y + ((size_t)b * S_DIM + t) * D_DIM;
      bf16x8 yr, yi;
#pragma unroll
      for (int j = 0; j < 8; ++j) { yr[j] = (bf16_t)zre[j]; yi[j] = (bf16_t)zim[j]; }
      ((bf16x8*)yrow)[lane]         = yr;
      ((bf16x8*)(yrow + 512))[lane] = yi;
    }
    cr = crn; ci = cin;
  }
}

extern "C" void kernel_launch(void* const* d_in, const int* in_sizes, int n_in,
                              void* d_out, int out_size, void* d_ws, size_t ws_size,
                              hipStream_t stream) {
  const float* x     = (const float*)d_in[0];
  const float* gamma = (const float*)d_in[1];
  const float* beta  = (const float*)d_in[2];
  const float* W_in  = (const float*)d_in[3];
  const float* b_in  = (const float*)d_in[4];
  const float* W_out = (const float*)d_in[5];
  const float* b_out = (const float*)d_in[6];
  float* out = (float*)d_out;

  char* ws = (char*)d_ws;
  bf16_t* hy  = (bf16_t*)(ws);                  // 32 MiB: h, later reused for y
  bf16_t* cbf = (bf16_t*)(ws + (32ull << 20));  // 32 MiB: c (bf16)
  bf16_t* wti = (bf16_t*)(ws + (64ull << 20));  // 2 MiB:  W_in^T bf16
  bf16_t* wto = (bf16_t*)(ws + (66ull << 20));  // 2 MiB:  W_out^T bf16

  transpose_kernel<<<dim3(32, 32), 256, 0, stream>>>(W_in, wti);
  transpose_kernel<<<dim3(32, 32), 256, 0, stream>>>(W_out, wto);
  ln_kernel<<<M_DIM, 64, 0, stream>>>(x, gamma, beta, hy);
  gemm_nt_kernel<0><<<256, 512, 0, stream>>>(hy, wti, b_in, nullptr, cbf);
  scan_kernel<<<dim3(S_DIM / CHUNK, B_DIM), 64, 0, stream>>>(cbf, hy);
  gemm_nt_kernel<1><<<256, 512, 0, stream>>>(hy, wto, b_out, x, out);
}

// Round 5
// 180.982 us; speedup vs baseline: 1.6069x; 1.6069x over previous
//
#include <hip/hip_runtime.h>

typedef __bf16 bf16_t;
typedef __bf16 bf16x8 __attribute__((ext_vector_type(8)));
typedef __bf16 bf16x4 __attribute__((ext_vector_type(4)));
typedef float  f32x4  __attribute__((ext_vector_type(4)));

#define B_DIM 4
#define S_DIM 4096
#define D_DIM 1024
#define M_DIM (B_DIM * S_DIM)   // 16384 rows

#define CHUNK 64   // scan output steps per block
#define WARM  24   // scan warm-up steps

__device__ __forceinline__ void g2l16(const void* g, void* l) {
  __builtin_amdgcn_global_load_lds(
      (const __attribute__((address_space(1))) void*)g,
      (__attribute__((address_space(3))) void*)l, 16, 0, 0);
}

// ---------------- LayerNorm fp32 -> bf16, one wave per row ----------------
__global__ __launch_bounds__(64) void ln_kernel(
    const float* __restrict__ x, const float* __restrict__ gamma,
    const float* __restrict__ beta, bf16_t* __restrict__ h) {
  const int row  = blockIdx.x;
  const int lane = threadIdx.x;
  const float4* xr = (const float4*)(x + (size_t)row * D_DIM);
  float4 v[4];
  float s = 0.f, s2 = 0.f;
#pragma unroll
  for (int j = 0; j < 4; ++j) {
    v[j] = xr[j * 64 + lane];
    s += v[j].x + v[j].y + v[j].z + v[j].w;
    s2 = fmaf(v[j].x, v[j].x, s2);
    s2 = fmaf(v[j].y, v[j].y, s2);
    s2 = fmaf(v[j].z, v[j].z, s2);
    s2 = fmaf(v[j].w, v[j].w, s2);
  }
#pragma unroll
  for (int off = 32; off; off >>= 1) {
    s  += __shfl_xor(s, off);
    s2 += __shfl_xor(s2, off);
  }
  const float mu  = s * (1.f / (float)D_DIM);
  const float var = fmaf(-mu, mu, s2 * (1.f / (float)D_DIM));
  const float inv = rsqrtf(var + 1e-5f);
  bf16_t* hr = h + (size_t)row * D_DIM;
#pragma unroll
  for (int j = 0; j < 4; ++j) {
    const float4 g4 = ((const float4*)gamma)[j * 64 + lane];
    const float4 b4 = ((const float4*)beta)[j * 64 + lane];
    bf16x4 o;
    o[0] = (bf16_t)fmaf((v[j].x - mu) * inv, g4.x, b4.x);
    o[1] = (bf16_t)fmaf((v[j].y - mu) * inv, g4.y, b4.y);
    o[2] = (bf16_t)fmaf((v[j].z - mu) * inv, g4.z, b4.z);
    o[3] = (bf16_t)fmaf((v[j].w - mu) * inv, g4.w, b4.w);
    ((bf16x4*)hr)[j * 64 + lane] = o;
  }
}

// ------------- W [K][N] fp32  ->  WT [N][K] bf16 (tiled transpose) --------
__global__ __launch_bounds__(256) void transpose_kernel(
    const float* __restrict__ W, bf16_t* __restrict__ WT) {
  __shared__ float tile[32][33];
  const int tx = threadIdx.x & 31;
  const int ty = threadIdx.x >> 5;
  const int bn = blockIdx.x * 32;
  const int bk = blockIdx.y * 32;
#pragma unroll
  for (int i = 0; i < 32; i += 8)
    tile[ty + i][tx] = W[(size_t)(bk + ty + i) * D_DIM + bn + tx];
  __syncthreads();
#pragma unroll
  for (int i = 0; i < 32; i += 8)
    WT[(size_t)(bn + ty + i) * D_DIM + bk + tx] = (bf16_t)tile[tx][ty + i];
}

// ====== bf16 NT GEMM, 128x128 tile, 4 waves, 4 blocks/CU (TLP focus) ======
// C[M][N] = A[M][K] * BT[N][K]^T ; MODE 0: bf16(acc+bias); MODE 1: f32 +x
// LDS per buffer: A [128 rows][64B] @0 (8KB) | B @8192 (8KB); double-buffered.
// Within a region, element (row,k) at 16B slot (k>>3)^((row>>1)&3) [0-conflict]
#define NTK 32   // K / 32

template <int MODE>
__global__ __launch_bounds__(256, 4) void gemm_nt_kernel(
    const bf16_t* __restrict__ A, const bf16_t* __restrict__ BT,
    const float* __restrict__ bias, const float* __restrict__ xres,
    void* __restrict__ Cout) {
  __shared__ __attribute__((aligned(16))) char lds[2][16384];
  const int tid  = threadIdx.x;
  const int lane = tid & 63;
  const int wave = tid >> 6;           // 0..3
  const int wr = wave >> 1;            // 0..1 (M half: 64 rows)
  const int wc = wave & 1;             // 0..1 (N half: 64 cols)
  const int bid = blockIdx.x;
  const int swz = (bid & 7) * 128 + (bid >> 3);   // 1024 blocks, 8 XCDs
  const int m0 = (swz >> 3) * 128;     // 128 m-panels
  const int n0 = (swz & 7) * 128;      // 8 n-panels

  // staging: thread covers (row = tid>>2, phys slot = tid&3); source k-elems
  // start at ((tid&3) ^ ((row>>1)&3))*8 = ((tid&3) ^ ((tid>>3)&3))*8
  const int ke = (((tid & 3) ^ ((tid >> 3) & 3)) << 3);
  const bf16_t* srcA = A  + (size_t)(m0 + (tid >> 2)) * D_DIM + ke;
  const bf16_t* srcB = BT + (size_t)(n0 + (tid >> 2)) * D_DIM + ke;
  const int l16 = tid * 16;

  // fragment bases: lane holds row (lane&15), logical k-group (lane>>4)
  const int sw   = (((lane >> 4) ^ ((lane >> 1) & 3)) << 4);
  const int aoff = (wr * 64 + (lane & 15)) * 64 + sw;
  const int boff = 8192 + (wc * 64 + (lane & 15)) * 64 + sw;

  f32x4 acc[4][4];
#pragma unroll
  for (int m = 0; m < 4; ++m)
#pragma unroll
    for (int n = 0; n < 4; ++n) acc[m][n] = (f32x4){0.f, 0.f, 0.f, 0.f};

#define STAGE(T)                                           \
  {                                                        \
    char* dst = lds[(T) & 1];                              \
    const size_t ko = (size_t)(T) * 32;                    \
    g2l16(srcA + ko, dst + l16);                           \
    g2l16(srcA + 65536 + ko, dst + 4096 + l16);            \
    g2l16(srcB + ko, dst + 8192 + l16);                    \
    g2l16(srcB + 65536 + ko, dst + 12288 + l16);           \
  }

  STAGE(0);
  for (int t = 0; t < NTK; ++t) {
    __syncthreads();  // drains stage(t) DMA; closes buf[(t+1)&1] readers
    const char* buf = lds[t & 1];
    bf16x8 a[4], b[4];
#pragma unroll
    for (int m = 0; m < 4; ++m) a[m] = *(const bf16x8*)(buf + aoff + m * 1024);
#pragma unroll
    for (int n = 0; n < 4; ++n) b[n] = *(const bf16x8*)(buf + boff + n * 1024);
    if (t + 1 < NTK) STAGE(t + 1);
#pragma unroll
    for (int m = 0; m < 4; ++m)
#pragma unroll
      for (int n = 0; n < 4; ++n)
        acc[m][n] = __builtin_amdgcn_mfma_f32_16x16x32_bf16(
            a[m], b[n], acc[m][n], 0, 0, 0);
  }
#undef STAGE

  // epilogue: C/D layout col = lane&15, row = (lane>>4)*4 + r
  const int rbase = m0 + wr * 64 + ((lane >> 4) << 2);
  const int cbase = n0 + wc * 64 + (lane & 15);
#pragma unroll
  for (int n = 0; n < 4; ++n) {
    const int col = cbase + n * 16;
    const float bn = bias[col];
#pragma unroll
    for (int m = 0; m < 4; ++m) {
      const int row = rbase + m * 16;
#pragma unroll
      for (int r = 0; r < 4; ++r) {
        const size_t idx = (size_t)(row + r) * D_DIM + col;
        if (MODE == 0)
          ((bf16_t*)Cout)[idx] = (bf16_t)(acc[m][n][r] + bn);
        else
          ((float*)Cout)[idx] = xres[idx] + acc[m][n][r] + bn;
      }
    }
  }
}

// ---------------- chunked chaotic scan, one wave per (batch, chunk) -------
__global__ __launch_bounds__(64) void scan_kernel(
    const bf16_t* __restrict__ c, bf16_t* __restrict__ y) {
  const int b     = blockIdx.y;
  const int chunk = blockIdx.x;
  const int t0    = chunk * CHUNK;
  const int start = (chunk == 0) ? 0 : t0 - WARM;
  const int tend  = t0 + CHUNK;
  const int lane  = threadIdx.x;

  float zre[8], zim[8];
#pragma unroll
  for (int j = 0; j < 8; ++j) { zre[j] = 0.f; zim[j] = 0.f; }

  const bf16_t* crow = c + ((size_t)b * S_DIM + start) * D_DIM;
  bf16x8 cr = ((const bf16x8*)crow)[lane];
  bf16x8 ci = ((const bf16x8*)(crow + 512))[lane];

  for (int t = start; t < tend; ++t) {
    bf16x8 crn = cr, cin = ci;
    if (t + 1 < tend) {
      const bf16_t* nrow = c + ((size_t)b * S_DIM + (t + 1)) * D_DIM;
      crn = ((const bf16x8*)nrow)[lane];
      cin = ((const bf16x8*)(nrow + 512))[lane];
    }
    float nr[8], ni[8];
    float ss = 0.f;
#pragma unroll
    for (int j = 0; j < 8; ++j) {
      const float a  = zre[j], bb = zim[j];
      const float rr = fmaf(a, a, fmaf(-bb, bb, (float)cr[j]));
      const float ii = fmaf(2.f * a, bb, (float)ci[j]);
      nr[j] = rr; ni[j] = ii;
      ss = fmaf(rr, rr, ss);
      ss = fmaf(ii, ii, ss);
    }
#pragma unroll
    for (int off = 32; off; off >>= 1) ss += __shfl_xor(ss, off);
    const float nrm = sqrtf(ss + 1e-12f);
    const float sc  = 2.0f / fmaxf(nrm, 2.0f);
#pragma unroll
    for (int j = 0; j < 8; ++j) { zre[j] = nr[j] * sc; zim[j] = ni[j] * sc; }
    if (t >= t0) {
      bf16_t* yrow = y + ((size_t)b * S_DIM + t) * D_DIM;
      bf16x8 yr, yi;
#pragma unroll
      for (int j = 0; j < 8; ++j) { yr[j] = (bf16_t)zre[j]; yi[j] = (bf16_t)zim[j]; }
      ((bf16x8*)yrow)[lane]         = yr;
      ((bf16x8*)(yrow + 512))[lane] = yi;
    }
    cr = crn; ci = cin;
  }
}

extern "C" void kernel_launch(void* const* d_in, const int* in_sizes, int n_in,
                              void* d_out, int out_size, void* d_ws, size_t ws_size,
                              hipStream_t stream) {
  const float* x     = (const float*)d_in[0];
  const float* gamma = (const float*)d_in[1];
  const float* beta  = (const float*)d_in[2];
  const float* W_in  = (const float*)d_in[3];
  const float* b_in  = (const float*)d_in[4];
  const float* W_out = (const float*)d_in[5];
  const float* b_out = (const float*)d_in[6];
  float* out = (float*)d_out;

  char* ws = (char*)d_ws;
  bf16_t* hy  = (bf16_t*)(ws);                  // 32 MiB: h, later reused for y
  bf16_t* cbf = (bf16_t*)(ws + (32ull << 20));  // 32 MiB: c (bf16)
  bf16_t* wti = (bf16_t*)(ws + (64ull << 20));  // 2 MiB:  W_in^T bf16
  bf16_t* wto = (bf16_t*)(ws + (66ull << 20));  // 2 MiB:  W_out^T bf16

  transpose_kernel<<<dim3(32, 32), 256, 0, stream>>>(W_in, wti);
  transpose_kernel<<<dim3(32, 32), 256, 0, stream>>>(W_out, wto);
  ln_kernel<<<M_DIM, 64, 0, stream>>>(x, gamma, beta, hy);
  gemm_nt_kernel<0><<<1024, 256, 0, stream>>>(hy, wti, b_in, nullptr, cbf);
  scan_kernel<<<dim3(S_DIM / CHUNK, B_DIM), 64, 0, stream>>>(cbf, hy);
  gemm_nt_kernel<1><<<1024, 256, 0, stream>>>(hy, wto, b_out, x, out);
}

// Round 6
// 172.067 us; speedup vs baseline: 1.6902x; 1.0518x over previous
//
#include <hip/hip_runtime.h>

typedef __bf16 bf16_t;
typedef __bf16 bf16x8 __attribute__((ext_vector_type(8)));
typedef __bf16 bf16x4 __attribute__((ext_vector_type(4)));
typedef float  f32x4  __attribute__((ext_vector_type(4)));

#define B_DIM 4
#define S_DIM 4096
#define D_DIM 1024
#define M_DIM (B_DIM * S_DIM)   // 16384 rows

#define CHUNK 64   // scan output steps per block
#define WARM  24   // scan warm-up steps

__device__ __forceinline__ void g2l16(const void* g, void* l) {
  __builtin_amdgcn_global_load_lds(
      (const __attribute__((address_space(1))) void*)g,
      (__attribute__((address_space(3))) void*)l, 16, 0, 0);
}

// ---------------- LayerNorm fp32 -> bf16, one wave per row ----------------
__global__ __launch_bounds__(64) void ln_kernel(
    const float* __restrict__ x, const float* __restrict__ gamma,
    const float* __restrict__ beta, bf16_t* __restrict__ h) {
  const int row  = blockIdx.x;
  const int lane = threadIdx.x;
  const float4* xr = (const float4*)(x + (size_t)row * D_DIM);
  float4 v[4];
  float s = 0.f, s2 = 0.f;
#pragma unroll
  for (int j = 0; j < 4; ++j) {
    v[j] = xr[j * 64 + lane];
    s += v[j].x + v[j].y + v[j].z + v[j].w;
    s2 = fmaf(v[j].x, v[j].x, s2);
    s2 = fmaf(v[j].y, v[j].y, s2);
    s2 = fmaf(v[j].z, v[j].z, s2);
    s2 = fmaf(v[j].w, v[j].w, s2);
  }
#pragma unroll
  for (int off = 32; off; off >>= 1) {
    s  += __shfl_xor(s, off);
    s2 += __shfl_xor(s2, off);
  }
  const float mu  = s * (1.f / (float)D_DIM);
  const float var = fmaf(-mu, mu, s2 * (1.f / (float)D_DIM));
  const float inv = rsqrtf(var + 1e-5f);
  bf16_t* hr = h + (size_t)row * D_DIM;
#pragma unroll
  for (int j = 0; j < 4; ++j) {
    const float4 g4 = ((const float4*)gamma)[j * 64 + lane];
    const float4 b4 = ((const float4*)beta)[j * 64 + lane];
    bf16x4 o;
    o[0] = (bf16_t)fmaf((v[j].x - mu) * inv, g4.x, b4.x);
    o[1] = (bf16_t)fmaf((v[j].y - mu) * inv, g4.y, b4.y);
    o[2] = (bf16_t)fmaf((v[j].z - mu) * inv, g4.z, b4.z);
    o[3] = (bf16_t)fmaf((v[j].w - mu) * inv, g4.w, b4.w);
    ((bf16x4*)hr)[j * 64 + lane] = o;
  }
}

// ------------- W [K][N] fp32  ->  WT [N][K] bf16 (tiled transpose) --------
__global__ __launch_bounds__(256) void transpose_kernel(
    const float* __restrict__ W, bf16_t* __restrict__ WT) {
  __shared__ float tile[32][33];
  const int tx = threadIdx.x & 31;
  const int ty = threadIdx.x >> 5;
  const int bn = blockIdx.x * 32;
  const int bk = blockIdx.y * 32;
#pragma unroll
  for (int i = 0; i < 32; i += 8)
    tile[ty + i][tx] = W[(size_t)(bk + ty + i) * D_DIM + bn + tx];
  __syncthreads();
#pragma unroll
  for (int i = 0; i < 32; i += 8)
    WT[(size_t)(bn + ty + i) * D_DIM + bk + tx] = (bf16_t)tile[tx][ty + i];
}

// ==== bf16 NT GEMM, 256x128 tile, 8 waves, ring-3 LDS, counted vmcnt ======
// C[M][N] = A[M][K] * BT[N][K]^T ; MODE 0: bf16(acc+bias); MODE 1: f32 +x
// Buffer (24 KB): A [256 rows][64B] @0 | B [128 rows][64B] @16384.
// (row,k) stored at 16B slot (k>>3)^((row>>1)&3)  [measured 0-conflict]
#define NTK 32        // K / 32
#define BUFSZ 24576

#define VMCNT(n) asm volatile("s_waitcnt vmcnt(" #n ")" ::: "memory")
#define DSR(d, a, off) \
  asm volatile("ds_read_b128 %0, %1 offset:" #off : "=v"(d) : "v"(a))

template <int MODE>
__global__ __launch_bounds__(512, 4) void gemm_nt_kernel(
    const bf16_t* __restrict__ A, const bf16_t* __restrict__ BT,
    const float* __restrict__ bias, const float* __restrict__ xres,
    void* __restrict__ Cout) {
  __shared__ __attribute__((aligned(16))) char lds[3][BUFSZ];
  const int tid  = threadIdx.x;
  const int lane = tid & 63;
  const int wave = tid >> 6;           // 0..7
  const int wr = wave >> 1;            // 0..3 (M quarter: 64 rows)
  const int wc = wave & 1;             // 0..1 (N half: 64 cols)
  const int bid = blockIdx.x;
  const int swz = (bid & 7) * 64 + (bid >> 3);   // 512 blocks, 8 XCDs
  const int m0 = (swz >> 3) * 256;     // 64 m-panels
  const int n0 = (swz & 7) * 128;      // 8 n-panels

  // convoy-breaking start stagger (hashed 0..7 x ~64 cyc)
  const int dly = (int)((bid * 2654435761u) >> 29);
  for (int i = 0; i < dly; ++i) __builtin_amdgcn_s_sleep(1);

  // staging: thread covers (row = tid>>2, phys slot = tid&3); source k-elems
  // start at ((tid&3) ^ ((row>>1)&3))*8
  const int ke = (((tid & 3) ^ ((tid >> 3) & 3)) << 3);
  const bf16_t* srcA = A  + (size_t)(m0 + (tid >> 2)) * D_DIM + ke;
  const bf16_t* srcB = BT + (size_t)(n0 + (tid >> 2)) * D_DIM + ke;
  const int l16 = tid * 16;

  // fragment bases
  const uint32_t lbase = (uint32_t)(uintptr_t)&lds[0][0];
  const int sw   = (((lane >> 4) ^ ((lane >> 1) & 3)) << 4);
  const uint32_t aoff = lbase + (uint32_t)((wr * 64 + (lane & 15)) * 64 + sw);
  const uint32_t boff = lbase + 16384u +
                        (uint32_t)((wc * 64 + (lane & 15)) * 64 + sw);

  f32x4 acc[4][4];
#pragma unroll
  for (int m = 0; m < 4; ++m)
#pragma unroll
    for (int n = 0; n < 4; ++n) acc[m][n] = (f32x4){0.f, 0.f, 0.f, 0.f};

#define STAGE(T, BI)                                       \
  {                                                        \
    char* dst = (char*)lds + (BI) * BUFSZ;                 \
    const size_t ko = (size_t)(T) * 32;                    \
    g2l16(srcA + ko, dst + l16);                           \
    g2l16(srcA + (size_t)128 * D_DIM + ko, dst + 8192 + l16); \
    g2l16(srcB + ko, dst + 16384 + l16);                   \
  }

#define STEP_BODY(CUR, DO_STAGE, T)                                 \
  {                                                                 \
    __builtin_amdgcn_s_barrier();                                   \
    const uint32_t bb = (uint32_t)(CUR) * BUFSZ;                    \
    bf16x8 af[4], bf[4];                                            \
    const uint32_t aA = aoff + bb;                                  \
    DSR(af[0], aA, 0);                                              \
    DSR(af[1], aA, 1024);                                           \
    DSR(af[2], aA, 2048);                                           \
    DSR(af[3], aA, 3072);                                           \
    const uint32_t bA = boff + bb;                                  \
    DSR(bf[0], bA, 0);                                              \
    DSR(bf[1], bA, 1024);                                           \
    DSR(bf[2], bA, 2048);                                           \
    DSR(bf[3], bA, 3072);                                           \
    if (DO_STAGE) { const int bi2 = (CUR) >= 1 ? (CUR) - 1 : (CUR) + 2; \
                    STAGE((T) + 2, bi2); }                          \
    asm volatile("s_waitcnt lgkmcnt(0)" ::: "memory");              \
    __builtin_amdgcn_sched_barrier(0);                              \
    __builtin_amdgcn_s_setprio(1);                                  \
    _Pragma("unroll") for (int m = 0; m < 4; ++m)                   \
        _Pragma("unroll") for (int n = 0; n < 4; ++n)               \
            acc[m][n] = __builtin_amdgcn_mfma_f32_16x16x32_bf16(    \
                af[m], bf[n], acc[m][n], 0, 0, 0);                  \
    __builtin_amdgcn_s_setprio(0);                                  \
  }

  STAGE(0, 0);
  STAGE(1, 1);
  int cur = 0;
  for (int t = 0; t < NTK - 1; ++t) {
    VMCNT(3);                    // own stage(t) retired; barrier makes global
    STEP_BODY(cur, t + 2 < NTK, t);
    cur = cur == 2 ? 0 : cur + 1;
  }
  VMCNT(0);
  STEP_BODY(cur, false, NTK - 1);

#undef STEP_BODY
#undef STAGE

  // epilogue: C/D layout col = lane&15, row = (lane>>4)*4 + r
  const int rbase = m0 + wr * 64 + ((lane >> 4) << 2);
  const int cbase = n0 + wc * 64 + (lane & 15);
#pragma unroll
  for (int n = 0; n < 4; ++n) {
    const int col = cbase + n * 16;
    const float bn = bias[col];
#pragma unroll
    for (int m = 0; m < 4; ++m) {
      const int row = rbase + m * 16;
#pragma unroll
      for (int r = 0; r < 4; ++r) {
        const size_t idx = (size_t)(row + r) * D_DIM + col;
        if (MODE == 0)
          ((bf16_t*)Cout)[idx] = (bf16_t)(acc[m][n][r] + bn);
        else
          ((float*)Cout)[idx] = xres[idx] + acc[m][n][r] + bn;
      }
    }
  }
}

// ---------------- chunked chaotic scan, one wave per (batch, chunk) -------
__global__ __launch_bounds__(64) void scan_kernel(
    const bf16_t* __restrict__ c, bf16_t* __restrict__ y) {
  const int b     = blockIdx.y;
  const int chunk = blockIdx.x;
  const int t0    = chunk * CHUNK;
  const int start = (chunk == 0) ? 0 : t0 - WARM;
  const int tend  = t0 + CHUNK;
  const int lane  = threadIdx.x;

  float zre[8], zim[8];
#pragma unroll
  for (int j = 0; j < 8; ++j) { zre[j] = 0.f; zim[j] = 0.f; }

  const bf16_t* crow = c + ((size_t)b * S_DIM + start) * D_DIM;
  bf16x8 cr = ((const bf16x8*)crow)[lane];
  bf16x8 ci = ((const bf16x8*)(crow + 512))[lane];

  for (int t = start; t < tend; ++t) {
    bf16x8 crn = cr, cin = ci;
    if (t + 1 < tend) {
      const bf16_t* nrow = c + ((size_t)b * S_DIM + (t + 1)) * D_DIM;
      crn = ((const bf16x8*)nrow)[lane];
      cin = ((const bf16x8*)(nrow + 512))[lane];
    }
    float nr[8], ni[8];
    float ss = 0.f;
#pragma unroll
    for (int j = 0; j < 8; ++j) {
      const float a  = zre[j], bb = zim[j];
      const float rr = fmaf(a, a, fmaf(-bb, bb, (float)cr[j]));
      const float ii = fmaf(2.f * a, bb, (float)ci[j]);
      nr[j] = rr; ni[j] = ii;
      ss = fmaf(rr, rr, ss);
      ss = fmaf(ii, ii, ss);
    }
#pragma unroll
    for (int off = 32; off; off >>= 1) ss += __shfl_xor(ss, off);
    const float nrm = sqrtf(ss + 1e-12f);
    const float sc  = 2.0f / fmaxf(nrm, 2.0f);
#pragma unroll
    for (int j = 0; j < 8; ++j) { zre[j] = nr[j] * sc; zim[j] = ni[j] * sc; }
    if (t >= t0) {
      bf16_t* yrow = y + ((size_t)b * S_DIM + t) * D_DIM;
      bf16x8 yr, yi;
#pragma unroll
      for (int j = 0; j < 8; ++j) { yr[j] = (bf16_t)zre[j]; yi[j] = (bf16_t)zim[j]; }
      ((bf16x8*)yrow)[lane]         = yr;
      ((bf16x8*)(yrow + 512))[lane] = yi;
    }
    cr = crn; ci = cin;
  }
}

extern "C" void kernel_launch(void* const* d_in, const int* in_sizes, int n_in,
                              void* d_out, int out_size, void* d_ws, size_t ws_size,
                              hipStream_t stream) {
  const float* x     = (const float*)d_in[0];
  const float* gamma = (const float*)d_in[1];
  const float* beta  = (const float*)d_in[2];
  const float* W_in  = (const float*)d_in[3];
  const float* b_in  = (const float*)d_in[4];
  const float* W_out = (const float*)d_in[5];
  const float* b_out = (const float*)d_in[6];
  float* out = (float*)d_out;

  char* ws = (char*)d_ws;
  bf16_t* hy  = (bf16_t*)(ws);                  // 32 MiB: h, later reused for y
  bf16_t* cbf = (bf16_t*)(ws + (32ull << 20));  // 32 MiB: c (bf16)
  bf16_t* wti = (bf16_t*)(ws + (64ull << 20));  // 2 MiB:  W_in^T bf16
  bf16_t* wto = (bf16_t*)(ws + (66ull << 20));  // 2 MiB:  W_out^T bf16

  transpose_kernel<<<dim3(32, 32), 256, 0, stream>>>(W_in, wti);
  transpose_kernel<<<dim3(32, 32), 256, 0, stream>>>(W_out, wto);
  ln_kernel<<<M_DIM, 64, 0, stream>>>(x, gamma, beta, hy);
  gemm_nt_kernel<0><<<512, 512, 0, stream>>>(hy, wti, b_in, nullptr, cbf);
  scan_kernel<<<dim3(S_DIM / CHUNK, B_DIM), 64, 0, stream>>>(cbf, hy);
  gemm_nt_kernel<1><<<512, 512, 0, stream>>>(hy, wto, b_out, x, out);
}